// Round 2
// baseline (3118.658 us; speedup 1.0000x reference)
//
#include <hip/hip_runtime.h>
#include <math.h>

// ---------- sizes (compile-time for this problem) ----------
#define B_  2
#define S_  512
#define P_  4096
#define TD_ 512
#define SD_ 384
#define H_  8
#define HD_ 64
#define FF_ 2048

// ---------------- block reduction (sum of two values) ----------------
__device__ __forceinline__ float2 block_sum2(float a, float b) {
    for (int off = 32; off > 0; off >>= 1) {
        a += __shfl_down(a, off);
        b += __shfl_down(b, off);
    }
    __shared__ float sa[8], sb[8];
    int w = threadIdx.x >> 6;
    if ((threadIdx.x & 63) == 0) { sa[w] = a; sb[w] = b; }
    __syncthreads();
    int nw = blockDim.x >> 6;
    float ta = 0.f, tb = 0.f;
    for (int i = 0; i < nw; ++i) { ta += sa[i]; tb += sb[i]; }
    __syncthreads();
    return make_float2(ta, tb);
}

// ---------------- LN: f32 in -> f32 out ----------------
__global__ __launch_bounds__(256) void ln_in_kernel(
    const float* __restrict__ x, const float* __restrict__ g,
    const float* __restrict__ be, float* __restrict__ y, int D)
{
    int row = blockIdx.x;
    const float* xr = x + (size_t)row * D;
    float s = 0.f, s2 = 0.f;
    for (int i = threadIdx.x; i < D; i += 256) {
        float v = xr[i]; s += v; s2 += v * v;
    }
    float2 r = block_sum2(s, s2);
    float mean = r.x / (float)D;
    float var  = r.y / (float)D - mean * mean;
    float rstd = rsqrtf(var + 1e-5f);
    float* yr = y + (size_t)row * D;
    for (int i = threadIdx.x; i < D; i += 256)
        yr[i] = (xr[i] - mean) * rstd * g[i] + be[i];
}

// ---------------- LN: (f32 residual + f32 x) -> f32 out ----------------
__global__ __launch_bounds__(256) void ln_res_kernel(
    const float* __restrict__ res, const float* __restrict__ x,
    const float* __restrict__ g, const float* __restrict__ be,
    float* __restrict__ y, int D)
{
    int row = blockIdx.x;
    const float* rr = res + (size_t)row * D;
    const float* xr = x + (size_t)row * D;
    float s = 0.f, s2 = 0.f;
    for (int i = threadIdx.x; i < D; i += 256) {
        float v = rr[i] + xr[i]; s += v; s2 += v * v;
    }
    float2 rd = block_sum2(s, s2);
    float mean = rd.x / (float)D;
    float var  = rd.y / (float)D - mean * mean;
    float rstd = rsqrtf(var + 1e-5f);
    float* yr = y + (size_t)row * D;
    for (int i = threadIdx.x; i < D; i += 256) {
        float v = rr[i] + xr[i];
        yr[i] = (v - mean) * rstd * g[i] + be[i];
    }
}

// ---------------- GEMM: C[MxN] = A[MxK] @ W[KxN] + bias, act 0=none 1=gelu ----------------
// 64x64 tile, BK=16, 256 threads, 4x4 per thread. M%64==0, N%64==0, K%16==0 assumed.
__global__ __launch_bounds__(256) void gemm_bias_kernel(
    const float* __restrict__ A, const float* __restrict__ W,
    const float* __restrict__ bias, float* __restrict__ C,
    int M, int N, int Kd, int act)
{
    __shared__ float As[16][64];
    __shared__ float Ws[16][64];
    int tid = threadIdx.x;
    int bm = blockIdx.y * 64;
    int bn = blockIdx.x * 64;
    int tx = tid & 15;   // n group
    int ty = tid >> 4;   // m group

    float acc[4][4];
#pragma unroll
    for (int i = 0; i < 4; ++i)
#pragma unroll
        for (int j = 0; j < 4; ++j) acc[i][j] = 0.f;

    // A-load indices
    int ar = tid >> 2;            // 0..63 row within tile
    int acg = (tid & 3) * 4;      // 0,4,8,12 col within tile
    // W-load indices
    int wr = tid >> 4;            // 0..15 k within tile
    int wcg = (tid & 15) * 4;     // 0..60 n within tile

    for (int k0 = 0; k0 < Kd; k0 += 16) {
        float4 av = *(const float4*)(A + (size_t)(bm + ar) * Kd + k0 + acg);
        As[acg + 0][ar] = av.x;
        As[acg + 1][ar] = av.y;
        As[acg + 2][ar] = av.z;
        As[acg + 3][ar] = av.w;

        float4 wv = *(const float4*)(W + (size_t)(k0 + wr) * N + bn + wcg);
        Ws[wr][wcg + 0] = wv.x;
        Ws[wr][wcg + 1] = wv.y;
        Ws[wr][wcg + 2] = wv.z;
        Ws[wr][wcg + 3] = wv.w;

        __syncthreads();
#pragma unroll
        for (int kk = 0; kk < 16; ++kk) {
            float a0 = As[kk][ty * 4 + 0];
            float a1 = As[kk][ty * 4 + 1];
            float a2 = As[kk][ty * 4 + 2];
            float a3 = As[kk][ty * 4 + 3];
            float w0 = Ws[kk][tx * 4 + 0];
            float w1 = Ws[kk][tx * 4 + 1];
            float w2 = Ws[kk][tx * 4 + 2];
            float w3 = Ws[kk][tx * 4 + 3];
            acc[0][0] = fmaf(a0, w0, acc[0][0]); acc[0][1] = fmaf(a0, w1, acc[0][1]);
            acc[0][2] = fmaf(a0, w2, acc[0][2]); acc[0][3] = fmaf(a0, w3, acc[0][3]);
            acc[1][0] = fmaf(a1, w0, acc[1][0]); acc[1][1] = fmaf(a1, w1, acc[1][1]);
            acc[1][2] = fmaf(a1, w2, acc[1][2]); acc[1][3] = fmaf(a1, w3, acc[1][3]);
            acc[2][0] = fmaf(a2, w0, acc[2][0]); acc[2][1] = fmaf(a2, w1, acc[2][1]);
            acc[2][2] = fmaf(a2, w2, acc[2][2]); acc[2][3] = fmaf(a2, w3, acc[2][3]);
            acc[3][0] = fmaf(a3, w0, acc[3][0]); acc[3][1] = fmaf(a3, w1, acc[3][1]);
            acc[3][2] = fmaf(a3, w2, acc[3][2]); acc[3][3] = fmaf(a3, w3, acc[3][3]);
        }
        __syncthreads();
    }

    float bv[4];
#pragma unroll
    for (int j = 0; j < 4; ++j) bv[j] = bias[bn + tx * 4 + j];

#pragma unroll
    for (int i = 0; i < 4; ++i) {
        int m = bm + ty * 4 + i;
        float4 o;
        float* op = (float*)&o;
#pragma unroll
        for (int j = 0; j < 4; ++j) {
            float v = acc[i][j] + bv[j];
            if (act == 1) v = 0.5f * v * (1.0f + erff(v * 0.70710678118654752f));
            op[j] = v;
        }
        *(float4*)(C + (size_t)m * N + bn + tx * 4) = o;
    }
}

// ---------------- LN: (f32 a + f32 c) -> f32 out ----------------
__global__ __launch_bounds__(256) void ln_final_kernel(
    const float* __restrict__ a, const float* __restrict__ c,
    const float* __restrict__ g, const float* __restrict__ be,
    float* __restrict__ y, int D)
{
    int row = blockIdx.x;
    const float* ar = a + (size_t)row * D;
    const float* cr = c + (size_t)row * D;
    float s = 0.f, s2 = 0.f;
    for (int i = threadIdx.x; i < D; i += 256) {
        float v = ar[i] + cr[i]; s += v; s2 += v * v;
    }
    float2 rd = block_sum2(s, s2);
    float mean = rd.x / (float)D;
    float var  = rd.y / (float)D - mean * mean;
    float rstd = rsqrtf(var + 1e-5f);
    float* yr = y + (size_t)row * D;
    for (int i = threadIdx.x; i < D; i += 256) {
        float v = ar[i] + cr[i];
        yr[i] = (v - mean) * rstd * g[i] + be[i];
    }
}

// ---------------- fused attention ----------------
// grid: B*H*(S/4) = 2048 blocks, 256 threads. Each block: 4 query rows of one (b,h).
__global__ __launch_bounds__(256) void attn_kernel(
    const float* __restrict__ Q, const float* __restrict__ Kb, const float* __restrict__ Vb,
    const float* __restrict__ edge_emb, const float* __restrict__ ep_w,
    const float* __restrict__ ep_b,
    float* __restrict__ attn_out, float* __restrict__ ctx)
{
    __shared__ float sc[4][P_];       // 64 KB scores -> probs
    __shared__ float qs[4][HD_];      // 1 KB
    __shared__ float part[4][4][HD_]; // 4 KB

    int bid = blockIdx.x;
    int i0 = (bid & 127) * 4;
    int h  = (bid >> 7) & 7;
    int b  = bid >> 10;
    int tid = threadIdx.x;

    {
        int r = tid >> 6, d = tid & 63;
        qs[r][d] = Q[((size_t)(b * S_ + i0 + r)) * TD_ + h * HD_ + d];
    }
    // per-head edge scalar (redundant per thread, tiny)
    float s_h = 0.f;
    for (int e = 0; e < 32; ++e) s_h += edge_emb[h * 32 + e] * ep_w[e];
    float epb = ep_b[0];
    __syncthreads();

    const float scale = 0.125f; // HD^-0.5
    // scores
    for (int p = tid; p < P_; p += 256) {
        const float4* kp = (const float4*)(Kb + ((size_t)(b * P_ + p)) * TD_ + h * HD_);
        float d0 = 0.f, d1 = 0.f, d2 = 0.f, d3 = 0.f;
#pragma unroll
        for (int j = 0; j < 16; ++j) {
            float4 kv = kp[j];
            float4 q0 = *(const float4*)&qs[0][j * 4];
            float4 q1 = *(const float4*)&qs[1][j * 4];
            float4 q2 = *(const float4*)&qs[2][j * 4];
            float4 q3 = *(const float4*)&qs[3][j * 4];
            d0 += kv.x * q0.x + kv.y * q0.y + kv.z * q0.z + kv.w * q0.w;
            d1 += kv.x * q1.x + kv.y * q1.y + kv.z * q1.z + kv.w * q1.w;
            d2 += kv.x * q2.x + kv.y * q2.y + kv.z * q2.z + kv.w * q2.w;
            d3 += kv.x * q3.x + kv.y * q3.y + kv.z * q3.z + kv.w * q3.w;
        }
        float base, z, e;
        base = d0 * scale; z = base * s_h + epb; e = (z >= 0.f) ? z : 0.2f * z; sc[0][p] = base + e;
        base = d1 * scale; z = base * s_h + epb; e = (z >= 0.f) ? z : 0.2f * z; sc[1][p] = base + e;
        base = d2 * scale; z = base * s_h + epb; e = (z >= 0.f) ? z : 0.2f * z; sc[2][p] = base + e;
        base = d3 * scale; z = base * s_h + epb; e = (z >= 0.f) ? z : 0.2f * z; sc[3][p] = base + e;
    }
    __syncthreads();

    // per-wave softmax: wave w handles row w
    {
        int w = tid >> 6, lane = tid & 63;
        float m = -INFINITY;
        for (int j = lane; j < P_; j += 64) m = fmaxf(m, sc[w][j]);
        for (int off = 32; off > 0; off >>= 1) m = fmaxf(m, __shfl_down(m, off));
        m = __shfl(m, 0);
        float sum = 0.f;
        for (int j = lane; j < P_; j += 64) {
            float e = expf(sc[w][j] - m);
            sc[w][j] = e;
            sum += e;
        }
        for (int off = 32; off > 0; off >>= 1) sum += __shfl_down(sum, off);
        sum = __shfl(sum, 0);
        float inv = 1.0f / sum;
        size_t arow = ((size_t)((b * H_ + h) * S_ + i0 + w)) * P_;
        for (int j = lane; j < P_; j += 64) {
            float a = sc[w][j] * inv;
            sc[w][j] = a;
            attn_out[arow + j] = a;
        }
    }
    __syncthreads();

    // ctx = attn @ V
    {
        int d = tid & 63, pp = tid >> 6;
        float a0 = 0.f, a1 = 0.f, a2 = 0.f, a3 = 0.f;
        for (int p = pp; p < P_; p += 4) {
            float vv = Vb[((size_t)(b * P_ + p)) * TD_ + h * HD_ + d];
            a0 = fmaf(sc[0][p], vv, a0);
            a1 = fmaf(sc[1][p], vv, a1);
            a2 = fmaf(sc[2][p], vv, a2);
            a3 = fmaf(sc[3][p], vv, a3);
        }
        part[0][pp][d] = a0; part[1][pp][d] = a1; part[2][pp][d] = a2; part[3][pp][d] = a3;
    }
    __syncthreads();
    {
        int rr = tid >> 6, dd = tid & 63;
        float o = part[rr][0][dd] + part[rr][1][dd] + part[rr][2][dd] + part[rr][3][dd];
        ctx[((size_t)(b * S_ + i0 + rr)) * TD_ + h * HD_ + dd] = o;
    }
}

extern "C" void kernel_launch(void* const* d_in, const int* in_sizes, int n_in,
                              void* d_out, int out_size, void* d_ws, size_t ws_size,
                              hipStream_t stream) {
    const float* text  = (const float*)d_in[0];
    const float* shape = (const float*)d_in[1];
    const float* tn_g  = (const float*)d_in[2];
    const float* tn_b  = (const float*)d_in[3];
    const float* sn_g  = (const float*)d_in[4];
    const float* sn_b  = (const float*)d_in[5];
    const float* Wq    = (const float*)d_in[6];
    const float* bq    = (const float*)d_in[7];
    const float* Wk    = (const float*)d_in[8];
    const float* bk    = (const float*)d_in[9];
    const float* Wv    = (const float*)d_in[10];
    const float* bv    = (const float*)d_in[11];
    const float* edge  = (const float*)d_in[12];
    const float* epw   = (const float*)d_in[13];
    const float* epb   = (const float*)d_in[14];
    const float* Wo    = (const float*)d_in[15];
    const float* bo    = (const float*)d_in[16];
    const float* on_g  = (const float*)d_in[17];
    const float* on_b  = (const float*)d_in[18];
    const float* W1    = (const float*)d_in[19];
    const float* b1    = (const float*)d_in[20];
    const float* W2    = (const float*)d_in[21];
    const float* b2    = (const float*)d_in[22];
    const float* fn_g  = (const float*)d_in[23];
    const float* fn_b  = (const float*)d_in[24];

    float* out_f  = (float*)d_out;                       // [B,S,TD]
    float* attn_f = out_f + (size_t)B_ * S_ * TD_;       // [B,H,S,P]

    // f32 workspace layout with reuse (total 12.58M floats = ~50.3 MB)
    float* ws = (float*)d_ws;
    float* tn   = ws;                       // 524288   (dead after Q gemm)
    float* sn   = tn + 524288;              // 3145728  (dead after K/V gemms)
    float* Qb   = sn + 3145728;             // 524288
    float* Kb   = Qb + 524288;              // 4194304  (dead after attn)
    float* Vb   = Kb + 4194304;             // 4194304  (dead after attn)
    float* ctx  = tn;                       // reuse tn region   (524288)
    float* tmp  = sn;                       // reuse sn region   (524288)
    float* out1 = sn + 524288;              // reuse sn region   (524288)
    float* h1   = Kb;                       // reuse Kb region   (2097152)

    // 1. LayerNorms of inputs
    ln_in_kernel<<<B_ * S_, 256, 0, stream>>>(text, tn_g, tn_b, tn, TD_);
    ln_in_kernel<<<B_ * P_, 256, 0, stream>>>(shape, sn_g, sn_b, sn, SD_);

    // 2. Q/K/V projections
    gemm_bias_kernel<<<dim3(TD_ / 64, (B_ * S_) / 64), 256, 0, stream>>>(tn, Wq, bq, Qb, B_ * S_, TD_, TD_, 0);
    gemm_bias_kernel<<<dim3(TD_ / 64, (B_ * P_) / 64), 256, 0, stream>>>(sn, Wk, bk, Kb, B_ * P_, TD_, SD_, 0);
    gemm_bias_kernel<<<dim3(TD_ / 64, (B_ * P_) / 64), 256, 0, stream>>>(sn, Wv, bv, Vb, B_ * P_, TD_, SD_, 0);

    // 3. fused attention (scores + edge + softmax + PV), writes attn f32 directly
    attn_kernel<<<B_ * H_ * (S_ / 4), 256, 0, stream>>>(Qb, Kb, Vb, edge, epw, epb, attn_f, ctx);

    // 4. output projection + residual LN
    gemm_bias_kernel<<<dim3(TD_ / 64, (B_ * S_) / 64), 256, 0, stream>>>(ctx, Wo, bo, tmp, B_ * S_, TD_, TD_, 0);
    ln_res_kernel<<<B_ * S_, 256, 0, stream>>>(text, tmp, on_g, on_b, out1, TD_);

    // 5. FFN
    gemm_bias_kernel<<<dim3(FF_ / 64, (B_ * S_) / 64), 256, 0, stream>>>(out1, W1, b1, h1, B_ * S_, FF_, TD_, 1);
    gemm_bias_kernel<<<dim3(TD_ / 64, (B_ * S_) / 64), 256, 0, stream>>>(h1, W2, b2, tmp, B_ * S_, TD_, FF_, 0);
    ln_final_kernel<<<B_ * S_, 256, 0, stream>>>(out1, tmp, fn_g, fn_b, out_f, TD_);
}

// Round 4
// 820.715 us; speedup vs baseline: 3.7999x; 3.7999x over previous
//
#include <hip/hip_runtime.h>
#include <math.h>

// ---------- sizes (compile-time for this problem) ----------
#define B_  2
#define S_  512
#define P_  4096
#define TD_ 512
#define SD_ 384
#define H_  8
#define HD_ 64
#define FF_ 2048

// ---------------- block reduction (sum of two values) ----------------
__device__ __forceinline__ float2 block_sum2(float a, float b) {
    for (int off = 32; off > 0; off >>= 1) {
        a += __shfl_down(a, off);
        b += __shfl_down(b, off);
    }
    __shared__ float sa[8], sb[8];
    int w = threadIdx.x >> 6;
    if ((threadIdx.x & 63) == 0) { sa[w] = a; sb[w] = b; }
    __syncthreads();
    int nw = blockDim.x >> 6;
    float ta = 0.f, tb = 0.f;
    for (int i = 0; i < nw; ++i) { ta += sa[i]; tb += sb[i]; }
    __syncthreads();
    return make_float2(ta, tb);
}

// ---------------- LN: f32 in -> f32 out ----------------
__global__ __launch_bounds__(256) void ln_in_kernel(
    const float* __restrict__ x, const float* __restrict__ g,
    const float* __restrict__ be, float* __restrict__ y, int D)
{
    int row = blockIdx.x;
    const float* xr = x + (size_t)row * D;
    float s = 0.f, s2 = 0.f;
    for (int i = threadIdx.x; i < D; i += 256) {
        float v = xr[i]; s += v; s2 += v * v;
    }
    float2 r = block_sum2(s, s2);
    float mean = r.x / (float)D;
    float var  = r.y / (float)D - mean * mean;
    float rstd = rsqrtf(var + 1e-5f);
    float* yr = y + (size_t)row * D;
    for (int i = threadIdx.x; i < D; i += 256)
        yr[i] = (xr[i] - mean) * rstd * g[i] + be[i];
}

// ---------------- LN: (f32 a + f32 c) -> f32 out ----------------
__global__ __launch_bounds__(256) void ln_add_kernel(
    const float* __restrict__ a, const float* __restrict__ c,
    const float* __restrict__ g, const float* __restrict__ be,
    float* __restrict__ y, int D)
{
    int row = blockIdx.x;
    const float* ar = a + (size_t)row * D;
    const float* cr = c + (size_t)row * D;
    float s = 0.f, s2 = 0.f;
    for (int i = threadIdx.x; i < D; i += 256) {
        float v = ar[i] + cr[i]; s += v; s2 += v * v;
    }
    float2 rd = block_sum2(s, s2);
    float mean = rd.x / (float)D;
    float var  = rd.y / (float)D - mean * mean;
    float rstd = rsqrtf(var + 1e-5f);
    float* yr = y + (size_t)row * D;
    for (int i = threadIdx.x; i < D; i += 256) {
        float v = ar[i] + cr[i];
        yr[i] = (v - mean) * rstd * g[i] + be[i];
    }
}

// ---------------- GEMM 64x64 tile: C = A @ W + bias, act 0=none 1=gelu ----------------
__global__ __launch_bounds__(256) void gemm_bias_kernel(
    const float* __restrict__ A, const float* __restrict__ W,
    const float* __restrict__ bias, float* __restrict__ C,
    int M, int N, int Kd, int act)
{
    __shared__ float As[16][64];
    __shared__ float Ws[16][64];
    int tid = threadIdx.x;
    int bm = blockIdx.y * 64;
    int bn = blockIdx.x * 64;
    int tx = tid & 15;
    int ty = tid >> 4;

    float acc[4][4];
#pragma unroll
    for (int i = 0; i < 4; ++i)
#pragma unroll
        for (int j = 0; j < 4; ++j) acc[i][j] = 0.f;

    int ar = tid >> 2;
    int acg = (tid & 3) * 4;
    int wr = tid >> 4;
    int wcg = (tid & 15) * 4;

    for (int k0 = 0; k0 < Kd; k0 += 16) {
        float4 av = *(const float4*)(A + (size_t)(bm + ar) * Kd + k0 + acg);
        As[acg + 0][ar] = av.x;
        As[acg + 1][ar] = av.y;
        As[acg + 2][ar] = av.z;
        As[acg + 3][ar] = av.w;

        float4 wv = *(const float4*)(W + (size_t)(k0 + wr) * N + bn + wcg);
        Ws[wr][wcg + 0] = wv.x;
        Ws[wr][wcg + 1] = wv.y;
        Ws[wr][wcg + 2] = wv.z;
        Ws[wr][wcg + 3] = wv.w;

        __syncthreads();
#pragma unroll
        for (int kk = 0; kk < 16; ++kk) {
            float4 aq = *(const float4*)&As[kk][ty * 4];
            float4 wq = *(const float4*)&Ws[kk][tx * 4];
            const float* aa = (const float*)&aq;
            const float* ww = (const float*)&wq;
#pragma unroll
            for (int i = 0; i < 4; ++i)
#pragma unroll
                for (int j = 0; j < 4; ++j)
                    acc[i][j] = fmaf(aa[i], ww[j], acc[i][j]);
        }
        __syncthreads();
    }

    float bv[4];
#pragma unroll
    for (int j = 0; j < 4; ++j) bv[j] = bias[bn + tx * 4 + j];

#pragma unroll
    for (int i = 0; i < 4; ++i) {
        int m = bm + ty * 4 + i;
        float4 o;
        float* op = (float*)&o;
#pragma unroll
        for (int j = 0; j < 4; ++j) {
            float v = acc[i][j] + bv[j];
            if (act == 1) v = 0.5f * v * (1.0f + erff(v * 0.70710678118654752f));
            op[j] = v;
        }
        *(float4*)(C + (size_t)m * N + bn + tx * 4) = o;
    }
}

// ---------------- GEMM 128x128 tile, BK=8, 8x8/thread (for M>=4096) ----------------
__global__ __launch_bounds__(256) void gemm128_kernel(
    const float* __restrict__ A, const float* __restrict__ W,
    const float* __restrict__ bias, float* __restrict__ C,
    int M, int N, int Kd)
{
    __shared__ float As[8][128];
    __shared__ float Ws[8][128];
    int tid = threadIdx.x;
    int bm = blockIdx.y * 128;
    int bn = blockIdx.x * 128;
    int tx = tid & 15;   // n: 8 cols at tx*8
    int ty = tid >> 4;   // m: 8 rows at ty*8

    float acc[8][8];
#pragma unroll
    for (int i = 0; i < 8; ++i)
#pragma unroll
        for (int j = 0; j < 8; ++j) acc[i][j] = 0.f;

    int ar = tid >> 1;            // 0..127
    int ac = (tid & 1) * 4;       // 0,4
    int wr = tid >> 5;            // 0..7
    int wc = (tid & 31) * 4;      // 0..124

    for (int k0 = 0; k0 < Kd; k0 += 8) {
        float4 av = *(const float4*)(A + (size_t)(bm + ar) * Kd + k0 + ac);
        As[ac + 0][ar] = av.x;
        As[ac + 1][ar] = av.y;
        As[ac + 2][ar] = av.z;
        As[ac + 3][ar] = av.w;

        float4 wv = *(const float4*)(W + (size_t)(k0 + wr) * N + bn + wc);
        Ws[wr][wc + 0] = wv.x;
        Ws[wr][wc + 1] = wv.y;
        Ws[wr][wc + 2] = wv.z;
        Ws[wr][wc + 3] = wv.w;

        __syncthreads();
#pragma unroll
        for (int kk = 0; kk < 8; ++kk) {
            float4 a0 = *(const float4*)&As[kk][ty * 8];
            float4 a1 = *(const float4*)&As[kk][ty * 8 + 4];
            float4 w0 = *(const float4*)&Ws[kk][tx * 8];
            float4 w1 = *(const float4*)&Ws[kk][tx * 8 + 4];
            float aa[8] = {a0.x, a0.y, a0.z, a0.w, a1.x, a1.y, a1.z, a1.w};
            float ww[8] = {w0.x, w0.y, w0.z, w0.w, w1.x, w1.y, w1.z, w1.w};
#pragma unroll
            for (int i = 0; i < 8; ++i)
#pragma unroll
                for (int j = 0; j < 8; ++j)
                    acc[i][j] = fmaf(aa[i], ww[j], acc[i][j]);
        }
        __syncthreads();
    }

    float bv[8];
#pragma unroll
    for (int j = 0; j < 8; ++j) bv[j] = bias[bn + tx * 8 + j];

#pragma unroll
    for (int i = 0; i < 8; ++i) {
        int m = bm + ty * 8 + i;
        float4 o0, o1;
        float* p0 = (float*)&o0;
        float* p1 = (float*)&o1;
#pragma unroll
        for (int j = 0; j < 4; ++j) { p0[j] = acc[i][j] + bv[j]; p1[j] = acc[i][j + 4] + bv[j + 4]; }
        *(float4*)(C + (size_t)m * N + bn + tx * 8) = o0;
        *(float4*)(C + (size_t)m * N + bn + tx * 8 + 4) = o1;
    }
}

// ---------------- attention scores: raw (base + edge) written to attn buffer ----------------
// grid: (P/64, S/64, B*H); 64x64 tile, K=64 contraction.
__global__ __launch_bounds__(256) void score_kernel(
    const float* __restrict__ Q, const float* __restrict__ Kb,
    const float* __restrict__ edge_emb, const float* __restrict__ ep_w,
    const float* __restrict__ ep_b, float* __restrict__ attn)
{
    __shared__ float Qs[64][64];  // [d][s]
    __shared__ float Ks[64][64];  // [d][p]
    int p0 = blockIdx.x * 64;
    int s0 = blockIdx.y * 64;
    int bh = blockIdx.z;
    int h = bh & 7, b = bh >> 3;
    int tid = threadIdx.x;

    // FIX (R3 bug): cover the FULL 64x64 tile. 4 threads per row; each thread
    // loads 4 float4s so all 64 d-values per row are staged.
    {
        int row = tid >> 2;           // 0..63
        int d0 = (tid & 3) * 16;      // 0,16,32,48
        const float* qrow = Q + (size_t)(b * S_ + s0 + row) * TD_ + h * HD_;
        const float* krow = Kb + (size_t)(b * P_ + p0 + row) * TD_ + h * HD_;
#pragma unroll
        for (int j = 0; j < 4; ++j) {
            int d = d0 + j * 4;
            float4 qv = *(const float4*)(qrow + d);
            Qs[d + 0][row] = qv.x; Qs[d + 1][row] = qv.y;
            Qs[d + 2][row] = qv.z; Qs[d + 3][row] = qv.w;
            float4 kv = *(const float4*)(krow + d);
            Ks[d + 0][row] = kv.x; Ks[d + 1][row] = kv.y;
            Ks[d + 2][row] = kv.z; Ks[d + 3][row] = kv.w;
        }
    }

    float s_h = 0.f;
#pragma unroll
    for (int e = 0; e < 32; ++e) s_h += edge_emb[h * 32 + e] * ep_w[e];
    float epb = ep_b[0];
    __syncthreads();

    int tx = tid & 15, ty = tid >> 4;
    float acc[4][4];
#pragma unroll
    for (int i = 0; i < 4; ++i)
#pragma unroll
        for (int j = 0; j < 4; ++j) acc[i][j] = 0.f;

#pragma unroll 4
    for (int kk = 0; kk < 64; ++kk) {
        float4 q4 = *(const float4*)&Qs[kk][ty * 4];
        float4 k4 = *(const float4*)&Ks[kk][tx * 4];
        const float* qq = (const float*)&q4;
        const float* kk4 = (const float*)&k4;
#pragma unroll
        for (int i = 0; i < 4; ++i)
#pragma unroll
            for (int j = 0; j < 4; ++j)
                acc[i][j] = fmaf(qq[i], kk4[j], acc[i][j]);
    }

    const float scale = 0.125f;
#pragma unroll
    for (int i = 0; i < 4; ++i) {
        size_t orow = ((size_t)bh * S_ + s0 + ty * 4 + i) * P_ + p0 + tx * 4;
        float4 o;
        float* op = (float*)&o;
#pragma unroll
        for (int j = 0; j < 4; ++j) {
            float base = acc[i][j] * scale;
            float z = base * s_h + epb;
            float e = (z >= 0.f) ? z : 0.2f * z;
            op[j] = base + e;
        }
        *(float4*)(attn + orow) = o;
    }
}

// ---------------- row softmax in place (attn: 8192 rows x 4096) ----------------
__global__ __launch_bounds__(256) void softmax_kernel(float* __restrict__ attn)
{
    size_t base = (size_t)blockIdx.x * P_;
    int tid = threadIdx.x;
    float4 v[4];
#pragma unroll
    for (int i = 0; i < 4; ++i)
        v[i] = *(const float4*)(attn + base + (size_t)(i * 256 + tid) * 4);

    float m = -INFINITY;
#pragma unroll
    for (int i = 0; i < 4; ++i) {
        m = fmaxf(m, fmaxf(fmaxf(v[i].x, v[i].y), fmaxf(v[i].z, v[i].w)));
    }
    // block max
    __shared__ float red[4];
    for (int off = 32; off > 0; off >>= 1) m = fmaxf(m, __shfl_down(m, off));
    if ((tid & 63) == 0) red[tid >> 6] = m;
    __syncthreads();
    m = fmaxf(fmaxf(red[0], red[1]), fmaxf(red[2], red[3]));
    __syncthreads();

    float s = 0.f;
#pragma unroll
    for (int i = 0; i < 4; ++i) {
        v[i].x = __expf(v[i].x - m); v[i].y = __expf(v[i].y - m);
        v[i].z = __expf(v[i].z - m); v[i].w = __expf(v[i].w - m);
        s += v[i].x + v[i].y + v[i].z + v[i].w;
    }
    for (int off = 32; off > 0; off >>= 1) s += __shfl_down(s, off);
    if ((tid & 63) == 0) red[tid >> 6] = s;
    __syncthreads();
    s = red[0] + red[1] + red[2] + red[3];
    float inv = 1.0f / s;

#pragma unroll
    for (int i = 0; i < 4; ++i) {
        v[i].x *= inv; v[i].y *= inv; v[i].z *= inv; v[i].w *= inv;
        *(float4*)(attn + base + (size_t)(i * 256 + tid) * 4) = v[i];
    }
}

// ---------------- PV: ctx[b,s,h*64+d] = sum_p attn[bh,s,p] * V[b,p,h*64+d] ----------------
// grid: (S/16, B*H); P tiled by 128.
__global__ __launch_bounds__(256) void pv_kernel(
    const float* __restrict__ attn, const float* __restrict__ Vb,
    float* __restrict__ ctx)
{
    __shared__ float At[16][128];
    __shared__ float Vt[128][64];
    int s0 = blockIdx.x * 16;
    int bh = blockIdx.y;
    int h = bh & 7, b = bh >> 3;
    int tid = threadIdx.x;
    int d = tid & 63;
    int sg = tid >> 6;    // 0..3; rows sg + 4*r

    float acc[4] = {0.f, 0.f, 0.f, 0.f};

    for (int p0 = 0; p0 < P_; p0 += 128) {
        // load attn tile 16x128
#pragma unroll
        for (int i = 0; i < 2; ++i) {
            int lin = (i * 256 + tid) * 4;
            int r = lin >> 7, c = lin & 127;
            *(float4*)&At[r][c] = *(const float4*)(attn + ((size_t)bh * S_ + s0 + r) * P_ + p0 + c);
        }
        // load V tile 128x64
#pragma unroll
        for (int i = 0; i < 8; ++i) {
            int lin = (i * 256 + tid) * 4;
            int vr = lin >> 6, vc = lin & 63;
            *(float4*)&Vt[vr][vc] = *(const float4*)(Vb + (size_t)(b * P_ + p0 + vr) * TD_ + h * HD_ + vc);
        }
        __syncthreads();
#pragma unroll 4
        for (int kk = 0; kk < 128; ++kk) {
            float vv = Vt[kk][d];
            acc[0] = fmaf(At[sg][kk],      vv, acc[0]);
            acc[1] = fmaf(At[sg + 4][kk],  vv, acc[1]);
            acc[2] = fmaf(At[sg + 8][kk],  vv, acc[2]);
            acc[3] = fmaf(At[sg + 12][kk], vv, acc[3]);
        }
        __syncthreads();
    }

#pragma unroll
    for (int r = 0; r < 4; ++r)
        ctx[(size_t)(b * S_ + s0 + sg + 4 * r) * TD_ + h * HD_ + d] = acc[r];
}

extern "C" void kernel_launch(void* const* d_in, const int* in_sizes, int n_in,
                              void* d_out, int out_size, void* d_ws, size_t ws_size,
                              hipStream_t stream) {
    const float* text  = (const float*)d_in[0];
    const float* shape = (const float*)d_in[1];
    const float* tn_g  = (const float*)d_in[2];
    const float* tn_b  = (const float*)d_in[3];
    const float* sn_g  = (const float*)d_in[4];
    const float* sn_b  = (const float*)d_in[5];
    const float* Wq    = (const float*)d_in[6];
    const float* bq    = (const float*)d_in[7];
    const float* Wk    = (const float*)d_in[8];
    const float* bk    = (const float*)d_in[9];
    const float* Wv    = (const float*)d_in[10];
    const float* bv    = (const float*)d_in[11];
    const float* edge  = (const float*)d_in[12];
    const float* epw   = (const float*)d_in[13];
    const float* epb   = (const float*)d_in[14];
    const float* Wo    = (const float*)d_in[15];
    const float* bo    = (const float*)d_in[16];
    const float* on_g  = (const float*)d_in[17];
    const float* on_b  = (const float*)d_in[18];
    const float* W1    = (const float*)d_in[19];
    const float* b1    = (const float*)d_in[20];
    const float* W2    = (const float*)d_in[21];
    const float* b2    = (const float*)d_in[22];
    const float* fn_g  = (const float*)d_in[23];
    const float* fn_b  = (const float*)d_in[24];

    float* out_f  = (float*)d_out;                       // [B,S,TD]
    float* attn_f = out_f + (size_t)B_ * S_ * TD_;       // [B,H,S,P]

    float* ws = (float*)d_ws;
    float* tn   = ws;                       // 524288   (dead after Q gemm)
    float* sn   = tn + 524288;              // 3145728  (dead after K/V gemms)
    float* Qb   = sn + 3145728;             // 524288
    float* Kb   = Qb + 524288;              // 4194304  (dead after score)
    float* Vb   = Kb + 4194304;             // 4194304  (dead after pv)
    float* ctx  = tn;                       // reuse tn region
    float* tmp  = sn;                       // reuse sn region
    float* out1 = sn + 524288;              // reuse sn region
    float* h1   = Kb;                       // reuse Kb region

    // 1. LayerNorms of inputs
    ln_in_kernel<<<B_ * S_, 256, 0, stream>>>(text, tn_g, tn_b, tn, TD_);
    ln_in_kernel<<<B_ * P_, 256, 0, stream>>>(shape, sn_g, sn_b, sn, SD_);

    // 2. Q/K/V projections (K/V use 128-tile: M=8192)
    gemm_bias_kernel<<<dim3(TD_ / 64, (B_ * S_) / 64), 256, 0, stream>>>(tn, Wq, bq, Qb, B_ * S_, TD_, TD_, 0);
    gemm128_kernel<<<dim3(TD_ / 128, (B_ * P_) / 128), 256, 0, stream>>>(sn, Wk, bk, Kb, B_ * P_, TD_, SD_);
    gemm128_kernel<<<dim3(TD_ / 128, (B_ * P_) / 128), 256, 0, stream>>>(sn, Wv, bv, Vb, B_ * P_, TD_, SD_);

    // 3. attention: scores -> softmax (in place in attn_f) -> PV
    score_kernel<<<dim3(P_ / 64, S_ / 64, B_ * H_), 256, 0, stream>>>(Qb, Kb, edge, epw, epb, attn_f);
    softmax_kernel<<<B_ * H_ * S_, 256, 0, stream>>>(attn_f);
    pv_kernel<<<dim3(S_ / 16, B_ * H_), 256, 0, stream>>>(attn_f, Vb, ctx);

    // 4. output projection + residual LN
    gemm_bias_kernel<<<dim3(TD_ / 64, (B_ * S_) / 64), 256, 0, stream>>>(ctx, Wo, bo, tmp, B_ * S_, TD_, TD_, 0);
    ln_add_kernel<<<B_ * S_, 256, 0, stream>>>(text, tmp, on_g, on_b, out1, TD_);

    // 5. FFN
    gemm_bias_kernel<<<dim3(FF_ / 64, (B_ * S_) / 64), 256, 0, stream>>>(out1, W1, b1, h1, B_ * S_, FF_, TD_, 1);
    gemm_bias_kernel<<<dim3(TD_ / 64, (B_ * S_) / 64), 256, 0, stream>>>(h1, W2, b2, tmp, B_ * S_, TD_, FF_, 0);
    ln_add_kernel<<<B_ * S_, 256, 0, stream>>>(out1, tmp, fn_g, fn_b, out_f, TD_);
}

// Round 5
// 462.502 us; speedup vs baseline: 6.7430x; 1.7745x over previous
//
#include <hip/hip_runtime.h>
#include <math.h>

// ---------- sizes (compile-time for this problem) ----------
#define B_  2
#define S_  512
#define P_  4096
#define TD_ 512
#define SD_ 384
#define H_  8
#define HD_ 64
#define FF_ 2048

typedef _Float16 half8 __attribute__((ext_vector_type(8)));
typedef _Float16 half4 __attribute__((ext_vector_type(4)));
typedef float floatx4 __attribute__((ext_vector_type(4)));

// ---------------- weight transpose + f16 cast: dst[n][k] = src[k][n] ----------------
__global__ __launch_bounds__(256) void wtrans_kernel(
    const float* __restrict__ src, _Float16* __restrict__ dst, int K, int N)
{
    __shared__ float ts[32][33];
    int k0 = blockIdx.y * 32, n0 = blockIdx.x * 32;
    int tid = threadIdx.x;
#pragma unroll
    for (int i = 0; i < 4; ++i) {
        int e = i * 256 + tid;
        int kk = e >> 5, nn = e & 31;
        ts[kk][nn] = src[(size_t)(k0 + kk) * N + n0 + nn];
    }
    __syncthreads();
#pragma unroll
    for (int i = 0; i < 4; ++i) {
        int e = i * 256 + tid;
        int nn = e >> 5, kk = e & 31;
        dst[(size_t)(n0 + nn) * K + k0 + kk] = (_Float16)ts[kk][nn];
    }
}

// ---------------- block reduction (sum of two values) ----------------
__device__ __forceinline__ float2 block_sum2(float a, float b) {
    for (int off = 32; off > 0; off >>= 1) {
        a += __shfl_down(a, off);
        b += __shfl_down(b, off);
    }
    __shared__ float sa[8], sb[8];
    int w = threadIdx.x >> 6;
    if ((threadIdx.x & 63) == 0) { sa[w] = a; sb[w] = b; }
    __syncthreads();
    int nw = blockDim.x >> 6;
    float ta = 0.f, tb = 0.f;
    for (int i = 0; i < nw; ++i) { ta += sa[i]; tb += sb[i]; }
    __syncthreads();
    return make_float2(ta, tb);
}

// ---------------- LN: f32 in -> f16 out ----------------
__global__ __launch_bounds__(256) void ln_in_f16_kernel(
    const float* __restrict__ x, const float* __restrict__ g,
    const float* __restrict__ be, _Float16* __restrict__ yh, int D)
{
    int row = blockIdx.x;
    const float* xr = x + (size_t)row * D;
    float s = 0.f, s2 = 0.f;
    for (int i = threadIdx.x; i < D; i += 256) {
        float v = xr[i]; s += v; s2 += v * v;
    }
    float2 r = block_sum2(s, s2);
    float mean = r.x / (float)D;
    float var  = r.y / (float)D - mean * mean;
    float rstd = rsqrtf(var + 1e-5f);
    _Float16* yr = yh + (size_t)row * D;
    for (int i = threadIdx.x; i < D; i += 256)
        yr[i] = (_Float16)((xr[i] - mean) * rstd * g[i] + be[i]);
}

// ---------------- LN: (f32 a + f32 c) -> f32 and/or f16 out ----------------
__global__ __launch_bounds__(256) void ln_add_kernel(
    const float* __restrict__ a, const float* __restrict__ c,
    const float* __restrict__ g, const float* __restrict__ be,
    float* __restrict__ yf, _Float16* __restrict__ yh, int D)
{
    int row = blockIdx.x;
    const float* ar = a + (size_t)row * D;
    const float* cr = c + (size_t)row * D;
    float s = 0.f, s2 = 0.f;
    for (int i = threadIdx.x; i < D; i += 256) {
        float v = ar[i] + cr[i]; s += v; s2 += v * v;
    }
    float2 rd = block_sum2(s, s2);
    float mean = rd.x / (float)D;
    float var  = rd.y / (float)D - mean * mean;
    float rstd = rsqrtf(var + 1e-5f);
    for (int i = threadIdx.x; i < D; i += 256) {
        float v = ar[i] + cr[i];
        float o = (v - mean) * rstd * g[i] + be[i];
        if (yf) yf[(size_t)row * D + i] = o;
        if (yh) yh[(size_t)row * D + i] = (_Float16)o;
    }
}

// ---------------- MFMA GEMM: C[M,N] = A[M,K] @ Bt[N,K]^T + bias ----------------
// 128x128 tile, BK=32, 4 waves each 64x64 (4x4 of 16x16x32 f16 MFMA).
// ACT: 1=gelu. OUTF: write f32 C. OUTH: write f16 C. VT: scatter f16 into Vt[(b,h,d)][p].
template<int ACT, int OUTF, int OUTH, int VT>
__global__ __launch_bounds__(256) void gemm_f16_kernel(
    const _Float16* __restrict__ A, const _Float16* __restrict__ Bt,
    const float* __restrict__ bias, float* __restrict__ Cf,
    _Float16* __restrict__ Ch, int M, int N, int K)
{
    __shared__ _Float16 As[128 * 40];   // stride 40 halves = 80B: 16B-aligned rows, ~2-way banks
    __shared__ _Float16 Bs[128 * 40];
    int tid = threadIdx.x;
    int bm = blockIdx.y * 128, bn = blockIdx.x * 128;
    int wave = tid >> 6, lane = tid & 63, quad = lane >> 4, r = lane & 15;
    int mh = (wave & 1) * 64, nh = (wave >> 1) * 64;

    floatx4 acc[4][4];
    floatx4 zz = {0.f, 0.f, 0.f, 0.f};
#pragma unroll
    for (int i = 0; i < 4; ++i)
#pragma unroll
        for (int j = 0; j < 4; ++j) acc[i][j] = zz;

    int srow = tid >> 2;          // 0..63
    int sko  = (tid & 3) * 8;     // 0,8,16,24

    for (int k0 = 0; k0 < K; k0 += 32) {
#pragma unroll
        for (int i = 0; i < 2; ++i) {
            int row = i * 64 + srow;
            *(half8*)&As[row * 40 + sko] = *(const half8*)(A  + (size_t)(bm + row) * K + k0 + sko);
            *(half8*)&Bs[row * 40 + sko] = *(const half8*)(Bt + (size_t)(bn + row) * K + k0 + sko);
        }
        __syncthreads();
        half8 af[4], bf[4];
#pragma unroll
        for (int t = 0; t < 4; ++t) {
            af[t] = *(const half8*)&As[(mh + t * 16 + r) * 40 + quad * 8];
            bf[t] = *(const half8*)&Bs[(nh + t * 16 + r) * 40 + quad * 8];
        }
#pragma unroll
        for (int i = 0; i < 4; ++i)
#pragma unroll
            for (int j = 0; j < 4; ++j)
                acc[i][j] = __builtin_amdgcn_mfma_f32_16x16x32_f16(af[i], bf[j], acc[i][j], 0, 0, 0);
        __syncthreads();
    }

    // C/D layout: col = lane&15, row = quad*4 + reg
#pragma unroll
    for (int j = 0; j < 4; ++j) {
        int col = bn + nh + j * 16 + r;
        float bv = bias[col];
#pragma unroll
        for (int i = 0; i < 4; ++i) {
#pragma unroll
            for (int g = 0; g < 4; ++g) {
                int row = bm + mh + i * 16 + quad * 4 + g;
                float v = acc[i][j][g] + bv;
                if (ACT) v = 0.5f * v * (1.0f + erff(v * 0.70710678118654752f));
                if (OUTF) Cf[(size_t)row * N + col] = v;
                if (OUTH) Ch[(size_t)row * N + col] = (_Float16)v;
                if (VT) {
                    int bb = row >> 12, pp = row & 4095;   // M rows = b*4096 + p
                    int hh = col >> 6,  dd = col & 63;     // N cols = h*64 + d
                    Ch[((size_t)((bb * 8 + hh) * 64 + dd)) * 4096 + pp] = (_Float16)v;
                }
            }
        }
    }
}

// ---------------- scores: S[s,p] = scale*Q.K^T, + edge leaky, raw f32 out ----------------
// grid (P/128, S/128, B*H). K-dim = HD = 64 (2 chunks of 32, staged at once).
__global__ __launch_bounds__(256) void score_f16_kernel(
    const _Float16* __restrict__ Qh, const _Float16* __restrict__ Kh,
    const float* __restrict__ edge_emb, const float* __restrict__ ep_w,
    const float* __restrict__ ep_b, float* __restrict__ attn)
{
    __shared__ _Float16 Qs[128 * 72];   // 64 k + 8 pad
    __shared__ _Float16 Ks[128 * 72];
    int p0 = blockIdx.x * 128, s0 = blockIdx.y * 128;
    int bh = blockIdx.z, h = bh & 7, b = bh >> 3;
    int tid = threadIdx.x;
    int wave = tid >> 6, lane = tid & 63, quad = lane >> 4, r = lane & 15;
    int mh = (wave & 1) * 64, nh = (wave >> 1) * 64;

#pragma unroll
    for (int i = 0; i < 4; ++i) {
        int row = i * 32 + (tid >> 3);
        int ko  = (tid & 7) * 8;
        *(half8*)&Qs[row * 72 + ko] = *(const half8*)(Qh + (size_t)(b * S_ + s0 + row) * TD_ + h * HD_ + ko);
        *(half8*)&Ks[row * 72 + ko] = *(const half8*)(Kh + (size_t)(b * P_ + p0 + row) * TD_ + h * HD_ + ko);
    }
    float s_h = 0.f;
#pragma unroll
    for (int e = 0; e < 32; ++e) s_h += edge_emb[h * 32 + e] * ep_w[e];
    float epb = ep_b[0];
    __syncthreads();

    floatx4 acc[4][4];
    floatx4 zz = {0.f, 0.f, 0.f, 0.f};
#pragma unroll
    for (int i = 0; i < 4; ++i)
#pragma unroll
        for (int j = 0; j < 4; ++j) acc[i][j] = zz;

#pragma unroll
    for (int c = 0; c < 2; ++c) {
        half8 af[4], bf[4];
#pragma unroll
        for (int t = 0; t < 4; ++t) {
            af[t] = *(const half8*)&Qs[(mh + t * 16 + r) * 72 + c * 32 + quad * 8];
            bf[t] = *(const half8*)&Ks[(nh + t * 16 + r) * 72 + c * 32 + quad * 8];
        }
#pragma unroll
        for (int i = 0; i < 4; ++i)
#pragma unroll
            for (int j = 0; j < 4; ++j)
                acc[i][j] = __builtin_amdgcn_mfma_f32_16x16x32_f16(af[i], bf[j], acc[i][j], 0, 0, 0);
    }

    const float scale = 0.125f;
#pragma unroll
    for (int i = 0; i < 4; ++i) {
#pragma unroll
        for (int j = 0; j < 4; ++j) {
#pragma unroll
            for (int g = 0; g < 4; ++g) {
                int row = s0 + mh + i * 16 + quad * 4 + g;
                int col = p0 + nh + j * 16 + r;
                float base = acc[i][j][g] * scale;
                float z = base * s_h + epb;
                float e = (z >= 0.f) ? z : 0.2f * z;
                attn[((size_t)bh * S_ + row) * P_ + col] = base + e;
            }
        }
    }
}

// ---------------- row softmax in place (attn: 8192 rows x 4096) ----------------
__global__ __launch_bounds__(256) void softmax_kernel(float* __restrict__ attn)
{
    size_t base = (size_t)blockIdx.x * P_;
    int tid = threadIdx.x;
    float4 v[4];
#pragma unroll
    for (int i = 0; i < 4; ++i)
        v[i] = *(const float4*)(attn + base + (size_t)(i * 256 + tid) * 4);

    float m = -INFINITY;
#pragma unroll
    for (int i = 0; i < 4; ++i)
        m = fmaxf(m, fmaxf(fmaxf(v[i].x, v[i].y), fmaxf(v[i].z, v[i].w)));
    __shared__ float red[4];
    for (int off = 32; off > 0; off >>= 1) m = fmaxf(m, __shfl_down(m, off));
    if ((tid & 63) == 0) red[tid >> 6] = m;
    __syncthreads();
    m = fmaxf(fmaxf(red[0], red[1]), fmaxf(red[2], red[3]));
    __syncthreads();

    float s = 0.f;
#pragma unroll
    for (int i = 0; i < 4; ++i) {
        v[i].x = __expf(v[i].x - m); v[i].y = __expf(v[i].y - m);
        v[i].z = __expf(v[i].z - m); v[i].w = __expf(v[i].w - m);
        s += v[i].x + v[i].y + v[i].z + v[i].w;
    }
    for (int off = 32; off > 0; off >>= 1) s += __shfl_down(s, off);
    if ((tid & 63) == 0) red[tid >> 6] = s;
    __syncthreads();
    s = red[0] + red[1] + red[2] + red[3];
    float inv = 1.0f / s;

#pragma unroll
    for (int i = 0; i < 4; ++i) {
        v[i].x *= inv; v[i].y *= inv; v[i].z *= inv; v[i].w *= inv;
        *(float4*)(attn + base + (size_t)(i * 256 + tid) * 4) = v[i];
    }
}

// ---------------- PV via MFMA: ctx[s, h*64+d] = sum_p attn[bh,s,p] * Vt[bh,d,p] ----------------
// grid (S/32, B*H). Tile 32s x 64d; 4 waves each 32x16; K=P in 32-chunks.
__global__ __launch_bounds__(256) void pv_f16_kernel(
    const float* __restrict__ attn, const _Float16* __restrict__ Vt,
    _Float16* __restrict__ ctx_h)
{
    __shared__ _Float16 As[32 * 40];
    __shared__ _Float16 Bs[64 * 40];
    int s0 = blockIdx.x * 32;
    int bh = blockIdx.y, h = bh & 7, b = bh >> 3;
    int tid = threadIdx.x;
    int wave = tid >> 6, lane = tid & 63, quad = lane >> 4, r = lane & 15;
    int no = wave * 16;

    floatx4 acc[2];
    floatx4 zz = {0.f, 0.f, 0.f, 0.f};
    acc[0] = zz; acc[1] = zz;

    int arow = tid >> 3, ako = (tid & 7) * 4;   // 32 rows x 4 f32 each
    int brow = tid >> 2, bko = (tid & 3) * 8;   // 64 rows x 8 halves each

    for (int k0 = 0; k0 < P_; k0 += 32) {
        float4 av = *(const float4*)(attn + ((size_t)bh * S_ + s0 + arow) * P_ + k0 + ako);
        half4 ah = { (_Float16)av.x, (_Float16)av.y, (_Float16)av.z, (_Float16)av.w };
        *(half4*)&As[arow * 40 + ako] = ah;
        *(half8*)&Bs[brow * 40 + bko] = *(const half8*)(Vt + ((size_t)bh * 64 + brow) * P_ + k0 + bko);
        __syncthreads();
        half8 bf = *(const half8*)&Bs[(no + r) * 40 + quad * 8];
#pragma unroll
        for (int t = 0; t < 2; ++t) {
            half8 af = *(const half8*)&As[(t * 16 + r) * 40 + quad * 8];
            acc[t] = __builtin_amdgcn_mfma_f32_16x16x32_f16(af, bf, acc[t], 0, 0, 0);
        }
        __syncthreads();
    }

#pragma unroll
    for (int t = 0; t < 2; ++t)
#pragma unroll
        for (int g = 0; g < 4; ++g) {
            int srow = s0 + t * 16 + quad * 4 + g;
            int d = no + r;
            ctx_h[(size_t)(b * S_ + srow) * TD_ + h * HD_ + d] = (_Float16)acc[t][g];
        }
}

extern "C" void kernel_launch(void* const* d_in, const int* in_sizes, int n_in,
                              void* d_out, int out_size, void* d_ws, size_t ws_size,
                              hipStream_t stream) {
    const float* text  = (const float*)d_in[0];
    const float* shape = (const float*)d_in[1];
    const float* tn_g  = (const float*)d_in[2];
    const float* tn_b  = (const float*)d_in[3];
    const float* sn_g  = (const float*)d_in[4];
    const float* sn_b  = (const float*)d_in[5];
    const float* Wq    = (const float*)d_in[6];
    const float* bq    = (const float*)d_in[7];
    const float* Wk    = (const float*)d_in[8];
    const float* bk    = (const float*)d_in[9];
    const float* Wv    = (const float*)d_in[10];
    const float* bv    = (const float*)d_in[11];
    const float* edge  = (const float*)d_in[12];
    const float* epw   = (const float*)d_in[13];
    const float* epb   = (const float*)d_in[14];
    const float* Wo    = (const float*)d_in[15];
    const float* bo    = (const float*)d_in[16];
    const float* on_g  = (const float*)d_in[17];
    const float* on_b  = (const float*)d_in[18];
    const float* W1    = (const float*)d_in[19];
    const float* b1    = (const float*)d_in[20];
    const float* W2    = (const float*)d_in[21];
    const float* b2    = (const float*)d_in[22];
    const float* fn_g  = (const float*)d_in[23];
    const float* fn_b  = (const float*)d_in[24];

    float* out_f  = (float*)d_out;                       // [B,S,TD]
    float* attn_f = out_f + (size_t)B_ * S_ * TD_;       // [B,H,S,P]

    // workspace layout (bytes) — total ~41.7 MB
    char* w = (char*)d_ws;
    _Float16* tn_h   = (_Float16*)w; w += (size_t)1024 * 512 * 2;
    _Float16* sn_h   = (_Float16*)w; w += (size_t)8192 * 384 * 2;
    _Float16* Q_h    = (_Float16*)w; w += (size_t)1024 * 512 * 2;
    _Float16* K_h    = (_Float16*)w; w += (size_t)8192 * 512 * 2;
    _Float16* Vt_h   = (_Float16*)w; w += (size_t)16 * 64 * 4096 * 2;
    _Float16* ctx_h  = (_Float16*)w; w += (size_t)1024 * 512 * 2;
    _Float16* out1_h = (_Float16*)w; w += (size_t)1024 * 512 * 2;
    _Float16* h1_h   = (_Float16*)w; w += (size_t)1024 * 2048 * 2;
    _Float16* Wqt    = (_Float16*)w; w += (size_t)512 * 512 * 2;
    _Float16* Wkt    = (_Float16*)w; w += (size_t)512 * 384 * 2;
    _Float16* Wvt    = (_Float16*)w; w += (size_t)512 * 384 * 2;
    _Float16* Wot    = (_Float16*)w; w += (size_t)512 * 512 * 2;
    _Float16* W1t    = (_Float16*)w; w += (size_t)2048 * 512 * 2;
    _Float16* W2t    = (_Float16*)w; w += (size_t)512 * 2048 * 2;
    float*    tmp    = (float*)w;    w += (size_t)1024 * 512 * 4;
    float*    out1_f = (float*)w;    w += (size_t)1024 * 512 * 4;

    // 0. weight transposes (f32 [K][N] -> f16 [N][K])
    wtrans_kernel<<<dim3(16, 16), 256, 0, stream>>>(Wq, Wqt, 512, 512);
    wtrans_kernel<<<dim3(16, 12), 256, 0, stream>>>(Wk, Wkt, 384, 512);
    wtrans_kernel<<<dim3(16, 12), 256, 0, stream>>>(Wv, Wvt, 384, 512);
    wtrans_kernel<<<dim3(16, 16), 256, 0, stream>>>(Wo, Wot, 512, 512);
    wtrans_kernel<<<dim3(64, 16), 256, 0, stream>>>(W1, W1t, 512, 2048);
    wtrans_kernel<<<dim3(16, 64), 256, 0, stream>>>(W2, W2t, 2048, 512);

    // 1. LayerNorms -> f16
    ln_in_f16_kernel<<<B_ * S_, 256, 0, stream>>>(text, tn_g, tn_b, tn_h, TD_);
    ln_in_f16_kernel<<<B_ * P_, 256, 0, stream>>>(shape, sn_g, sn_b, sn_h, SD_);

    // 2. Q/K/V projections (MFMA); V written transposed into Vt
    gemm_f16_kernel<0,0,1,0><<<dim3(4, 8),  256, 0, stream>>>(tn_h, Wqt, bq, nullptr, Q_h, 1024, 512, 512);
    gemm_f16_kernel<0,0,1,0><<<dim3(4, 64), 256, 0, stream>>>(sn_h, Wkt, bk, nullptr, K_h, 8192, 512, 384);
    gemm_f16_kernel<0,0,0,1><<<dim3(4, 64), 256, 0, stream>>>(sn_h, Wvt, bv, nullptr, Vt_h, 8192, 512, 384);

    // 3. attention
    score_f16_kernel<<<dim3(P_ / 128, S_ / 128, B_ * H_), 256, 0, stream>>>(Q_h, K_h, edge, epw, epb, attn_f);
    softmax_kernel<<<B_ * H_ * S_, 256, 0, stream>>>(attn_f);
    pv_f16_kernel<<<dim3(S_ / 32, B_ * H_), 256, 0, stream>>>(attn_f, Vt_h, ctx_h);

    // 4. output projection + residual LN
    gemm_f16_kernel<0,1,0,0><<<dim3(4, 8), 256, 0, stream>>>(ctx_h, Wot, bo, tmp, nullptr, 1024, 512, 512);
    ln_add_kernel<<<B_ * S_, 256, 0, stream>>>(text, tmp, on_g, on_b, out1_f, out1_h, TD_);

    // 5. FFN (gelu fused in FFN1 epilogue)
    gemm_f16_kernel<1,0,1,0><<<dim3(16, 8), 256, 0, stream>>>(out1_h, W1t, b1, nullptr, h1_h, 1024, 2048, 512);
    gemm_f16_kernel<0,1,0,0><<<dim3(4, 8),  256, 0, stream>>>(h1_h, W2t, b2, tmp, nullptr, 1024, 512, 2048);
    ln_add_kernel<<<B_ * S_, 256, 0, stream>>>(out1_f, tmp, fn_g, fn_b, out_f, nullptr, TD_);
}